// Round 2
// baseline (432.615 us; speedup 1.0000x reference)
//
#include <hip/hip_runtime.h>
#include <stdint.h>

// Problem constants (reference file)
#define B_TOT 4096
#define SEQ   64
#define Y_DIM 256
#define H_DIM 128
#define E_DIM 32
#define KG_N  8
#define KA_N  20
#define NC_N  50
#define NT_N  5

#define ROWS 8                 // rows (samples) per block
#define NBLK (B_TOT / ROWS)    // 512 blocks

// Output offsets (flat f32, return-order concat)
#define O_COUNTRY 0
#define O_TYPE    (B_TOT * NC_N)                  // 204800
#define O_TASTE   (O_TYPE + B_TOT)                // 208896
#define O_GPRED   (O_TASTE + B_TOT * NT_N)        // 229376
#define O_GTRUE   (O_GPRED + B_TOT * KG_N)        // 262144
#define O_APRED   (O_GTRUE + B_TOT * KG_N)        // 294912
#define O_ATRUE   (O_APRED + B_TOT * KA_N)        // 376832

__device__ __forceinline__ float sigmoidf_(float x) { return 1.0f / (1.0f + __expf(-x)); }

__global__ __launch_bounds__(256) void wine_fused_kernel(
    const float* __restrict__ x_enc,          // [B,S,Y] f32
    const int*   __restrict__ grapes,         // [B,KG] i32
    const float* __restrict__ grapes_scales,  // [B,KG] f32
    const int*   __restrict__ aromas,         // [B,KA] i32
    const float* __restrict__ aromas_scales,  // [B,KA] f32
    const float* __restrict__ W_common,       // [Y,H]
    const float* __restrict__ b_common,       // [H]
    const float* __restrict__ W_country,      // [H,NC]
    const float* __restrict__ b_country,      // [NC]
    const float* __restrict__ W_type,         // [H,1]
    const float* __restrict__ b_type,         // [1]
    const float* __restrict__ W_taste,        // [H,NT]
    const float* __restrict__ b_taste,        // [NT]
    const float* __restrict__ W_aroma,        // [H,E]
    const float* __restrict__ b_aroma,        // [E]
    const float* __restrict__ W_grape,        // [H,E]
    const float* __restrict__ b_grape,        // [E]
    const float* __restrict__ grapes_emb,     // [VG,E]
    const float* __restrict__ aroma_emb,      // [VA,E]
    float*       __restrict__ out)
{
    __shared__ float xs[ROWS][Y_DIM];            // max-pooled x
    __shared__ float ys[ROWS][H_DIM];            // elu(common)
    __shared__ float yg[ROWS][E_DIM + 1];        // +1 pad: breaks 8-way bank alias
    __shared__ float ya[ROWS][E_DIM + 1];

    const int t  = threadIdx.x;
    const int b0 = blockIdx.x * ROWS;

    // ---------- Phase 1: max over sequence (the 268 MB stream) ----------
    {
        const int row = t >> 5;                  // 0..7
        const int y0  = (t & 31) * 8;            // 8 floats per lane (2x float4)
        const float* xp = x_enc + (size_t)(b0 + row) * SEQ * Y_DIM + y0;
        float m[8];
        #pragma unroll
        for (int i = 0; i < 8; ++i) m[i] = -3.4e38f;
        #pragma unroll 8
        for (int s = 0; s < SEQ; ++s) {
            float4 a = *(const float4*)(xp + (size_t)s * Y_DIM);
            float4 b = *(const float4*)(xp + (size_t)s * Y_DIM + 4);
            m[0] = fmaxf(m[0], a.x); m[1] = fmaxf(m[1], a.y);
            m[2] = fmaxf(m[2], a.z); m[3] = fmaxf(m[3], a.w);
            m[4] = fmaxf(m[4], b.x); m[5] = fmaxf(m[5], b.y);
            m[6] = fmaxf(m[6], b.z); m[7] = fmaxf(m[7], b.w);
        }
        float4* dst = (float4*)&xs[row][y0];
        dst[0] = make_float4(m[0], m[1], m[2], m[3]);
        dst[1] = make_float4(m[4], m[5], m[6], m[7]);
    }
    __syncthreads();

    // ---------- Phase 2: y = elu(x @ W_common + b_common) ----------
    {
        const int row = t >> 5;
        const int h0  = (t & 31) * 4;            // 4 h-columns per lane
        float a0 = 0.f, a1 = 0.f, a2 = 0.f, a3 = 0.f;
        const float* Wp = W_common + h0;
        #pragma unroll 4
        for (int k = 0; k < Y_DIM; ++k) {
            float xv = xs[row][k];               // broadcast LDS read
            float4 w = *(const float4*)(Wp + (size_t)k * H_DIM);  // coalesced 16B, L2-hot
            a0 += xv * w.x; a1 += xv * w.y;
            a2 += xv * w.z; a3 += xv * w.w;
        }
        float4 bb = *(const float4*)(b_common + h0);
        a0 += bb.x; a1 += bb.y; a2 += bb.z; a3 += bb.w;
        // ELU (alpha=1)
        a0 = (a0 > 0.f) ? a0 : (__expf(a0) - 1.f);
        a1 = (a1 > 0.f) ? a1 : (__expf(a1) - 1.f);
        a2 = (a2 > 0.f) ? a2 : (__expf(a2) - 1.f);
        a3 = (a3 > 0.f) ? a3 : (__expf(a3) - 1.f);
        *(float4*)&ys[row][h0] = make_float4(a0, a1, a2, a3);
    }
    __syncthreads();

    // ---------- Phase 3: head dots (120 columns per row) ----------
    // c: [0,50) country | 50 type | [51,56) taste | [56,88) grape-emb | [88,120) aroma-emb
    for (int j = t; j < ROWS * 120; j += 256) {
        const int row = j / 120;
        const int c   = j - row * 120;
        const float* Wp;
        int stride;
        if (c < 50)       { Wp = W_country + c;        stride = NC_N;  }
        else if (c == 50) { Wp = W_type;               stride = 1;     }
        else if (c < 56)  { Wp = W_taste + (c - 51);   stride = NT_N;  }
        else if (c < 88)  { Wp = W_grape + (c - 56);   stride = E_DIM; }
        else              { Wp = W_aroma + (c - 88);   stride = E_DIM; }
        float acc = 0.f;
        const float* yv = ys[row];
        #pragma unroll 4
        for (int k = 0; k < H_DIM; ++k)
            acc += yv[k] * Wp[(size_t)k * stride];
        const int b = b0 + row;
        if (c < 50) {
            out[O_COUNTRY + (size_t)b * NC_N + c] = acc + b_country[c];
        } else if (c == 50) {
            out[O_TYPE + b] = sigmoidf_(acc + b_type[0]);
        } else if (c < 56) {
            out[O_TASTE + (size_t)b * NT_N + (c - 51)] = sigmoidf_(acc + b_taste[c - 51]);
        } else if (c < 88) {
            yg[row][c - 56] = acc + b_grape[c - 56];
        } else {
            ya[row][c - 88] = acc + b_aroma[c - 88];
        }
    }
    __syncthreads();

    // ---------- Phase 4: ragged gathers ----------
    if (t < ROWS * KG_N) {                       // 64 grape jobs
        const int row  = t >> 3;
        const int gi   = (b0 + row) * KG_N + (t & 7);
        const int idx  = grapes[gi];
        float pred = 0.f;
        if (idx != 0) {
            const float* ep = grapes_emb + (size_t)idx * E_DIM;
            const float* yv = yg[row];
            float acc = 0.f;
            #pragma unroll
            for (int e = 0; e < E_DIM; e += 4) {
                float4 v = *(const float4*)(ep + e);
                acc += yv[e+0]*v.x + yv[e+1]*v.y + yv[e+2]*v.z + yv[e+3]*v.w;
            }
            pred = sigmoidf_(acc);
        }
        out[O_GPRED + gi] = pred;
        out[O_GTRUE + gi] = grapes_scales[gi];   // scales >= 0; scales*(scales!=0) == scales
    } else if (t < ROWS * (KG_N + KA_N)) {       // 160 aroma jobs
        const int j    = t - ROWS * KG_N;
        const int row  = j / KA_N;
        const int ai   = (b0 + row) * KA_N + (j - row * KA_N);
        const float sc = aromas_scales[ai];
        float pred = 0.f;
        if (sc != 0.f) {                         // mask = (scales != 0)
            const int idx = aromas[ai];
            const float* ep = aroma_emb + (size_t)idx * E_DIM;
            const float* yv = ya[row];
            float acc = 0.f;
            #pragma unroll
            for (int e = 0; e < E_DIM; e += 4) {
                float4 v = *(const float4*)(ep + e);
                acc += yv[e+0]*v.x + yv[e+1]*v.y + yv[e+2]*v.z + yv[e+3]*v.w;
            }
            pred = sigmoidf_(acc);
        }
        out[O_APRED + ai] = pred;
        out[O_ATRUE + ai] = sc;                  // scales * mask == scales
    }
}

extern "C" void kernel_launch(void* const* d_in, const int* in_sizes, int n_in,
                              void* d_out, int out_size, void* d_ws, size_t ws_size,
                              hipStream_t stream) {
    (void)in_sizes; (void)n_in; (void)d_ws; (void)ws_size; (void)out_size;
    const float* x_enc         = (const float*)d_in[0];
    const int*   grapes        = (const int*)  d_in[1];
    const float* grapes_scales = (const float*)d_in[2];
    const int*   aromas        = (const int*)  d_in[3];
    const float* aromas_scales = (const float*)d_in[4];
    const float* W_common      = (const float*)d_in[5];
    const float* b_common      = (const float*)d_in[6];
    const float* W_country     = (const float*)d_in[7];
    const float* b_country     = (const float*)d_in[8];
    const float* W_type        = (const float*)d_in[9];
    const float* b_type        = (const float*)d_in[10];
    const float* W_taste       = (const float*)d_in[11];
    const float* b_taste       = (const float*)d_in[12];
    const float* W_aroma       = (const float*)d_in[13];
    const float* b_aroma       = (const float*)d_in[14];
    const float* W_grape       = (const float*)d_in[15];
    const float* b_grape       = (const float*)d_in[16];
    const float* grapes_emb    = (const float*)d_in[17];
    const float* aroma_emb     = (const float*)d_in[18];
    float* out = (float*)d_out;

    hipLaunchKernelGGL(wine_fused_kernel, dim3(NBLK), dim3(256), 0, stream,
                       x_enc, grapes, grapes_scales, aromas, aromas_scales,
                       W_common, b_common, W_country, b_country, W_type, b_type,
                       W_taste, b_taste, W_aroma, b_aroma, W_grape, b_grape,
                       grapes_emb, aroma_emb, out);
}

// Round 3
// 413.153 us; speedup vs baseline: 1.0471x; 1.0471x over previous
//
#include <hip/hip_runtime.h>
#include <stdint.h>

// Problem constants (reference file)
#define B_TOT 4096
#define SEQ   64
#define Y_DIM 256
#define H_DIM 128
#define E_DIM 32
#define KG_N  8
#define KA_N  20
#define NC_N  50
#define NT_N  5

#define ROWS 4                 // rows (samples) per block
#define NBLK (B_TOT / ROWS)    // 1024 blocks -> 4 blocks/CU, 16 waves/CU

// Output offsets (flat f32, return-order concat)
#define O_COUNTRY 0
#define O_TYPE    (B_TOT * NC_N)                  // 204800
#define O_TASTE   (O_TYPE + B_TOT)                // 208896
#define O_GPRED   (O_TASTE + B_TOT * NT_N)        // 229376
#define O_GTRUE   (O_GPRED + B_TOT * KG_N)        // 262144
#define O_APRED   (O_GTRUE + B_TOT * KG_N)        // 294912
#define O_ATRUE   (O_APRED + B_TOT * KA_N)        // 376832

typedef float f4 __attribute__((ext_vector_type(4)));

__device__ __forceinline__ float sigmoidf_(float x) { return 1.0f / (1.0f + __expf(-x)); }

__global__ __launch_bounds__(256) void wine_fused_kernel(
    const float* __restrict__ x_enc,          // [B,S,Y] f32
    const int*   __restrict__ grapes,         // [B,KG] i32
    const float* __restrict__ grapes_scales,  // [B,KG] f32
    const int*   __restrict__ aromas,         // [B,KA] i32
    const float* __restrict__ aromas_scales,  // [B,KA] f32
    const float* __restrict__ W_common,       // [Y,H]
    const float* __restrict__ b_common,       // [H]
    const float* __restrict__ W_country,      // [H,NC]
    const float* __restrict__ b_country,      // [NC]
    const float* __restrict__ W_type,         // [H,1]
    const float* __restrict__ b_type,         // [1]
    const float* __restrict__ W_taste,        // [H,NT]
    const float* __restrict__ b_taste,        // [NT]
    const float* __restrict__ W_aroma,        // [H,E]
    const float* __restrict__ b_aroma,        // [E]
    const float* __restrict__ W_grape,        // [H,E]
    const float* __restrict__ b_grape,        // [E]
    const float* __restrict__ grapes_emb,     // [VG,E]
    const float* __restrict__ aroma_emb,      // [VA,E]
    float*       __restrict__ out)
{
    __shared__ float xs[ROWS][Y_DIM];            // max-pooled x      (4 KB)
    __shared__ float ys[ROWS][H_DIM];            // elu(common)       (2 KB)
    __shared__ float yg[ROWS][E_DIM + 1];        // +1 pad vs bank alias
    __shared__ float ya[ROWS][E_DIM + 1];

    const int t  = threadIdx.x;
    const int b0 = blockIdx.x * ROWS;

    // ---------- Phase 1: max over sequence (the 268 MB stream) ----------
    // One wave per row; lane owns one float4 -> each instruction reads a
    // contiguous 1 KiB row segment. Nontemporal: read-once, skip L2 fill.
    {
        const int row = t >> 6;                  // 0..3
        const int y0  = (t & 63) * 4;            // 4 floats per lane
        const float* xp = x_enc + (size_t)(b0 + row) * SEQ * Y_DIM + y0;
        f4 m = { -3.4e38f, -3.4e38f, -3.4e38f, -3.4e38f };
        #pragma unroll 8
        for (int s = 0; s < SEQ; ++s) {
            f4 a = __builtin_nontemporal_load((const f4*)(xp + (size_t)s * Y_DIM));
            m.x = fmaxf(m.x, a.x); m.y = fmaxf(m.y, a.y);
            m.z = fmaxf(m.z, a.z); m.w = fmaxf(m.w, a.w);
        }
        *(f4*)&xs[row][y0] = m;
    }
    __syncthreads();

    // ---------- Phase 2: y = elu(x @ W_common + b_common) ----------
    {
        const int row = t >> 6;
        const int h0  = (t & 63) * 2;            // 2 h-columns per lane
        float a0 = 0.f, a1 = 0.f;
        const float* Wp = W_common + h0;
        #pragma unroll 8
        for (int k = 0; k < Y_DIM; ++k) {
            float xv = xs[row][k];               // broadcast LDS read
            float2 w = *(const float2*)(Wp + (size_t)k * H_DIM);  // coalesced 8B, L2-hot
            a0 += xv * w.x; a1 += xv * w.y;
        }
        float2 bb = *(const float2*)(b_common + h0);
        a0 += bb.x; a1 += bb.y;
        // ELU (alpha=1)
        a0 = (a0 > 0.f) ? a0 : (__expf(a0) - 1.f);
        a1 = (a1 > 0.f) ? a1 : (__expf(a1) - 1.f);
        *(float2*)&ys[row][h0] = make_float2(a0, a1);
    }
    __syncthreads();

    // ---------- Phase 3: head dots (120 columns per row) ----------
    // c: [0,50) country | 50 type | [51,56) taste | [56,88) grape-emb | [88,120) aroma-emb
    for (int j = t; j < ROWS * 120; j += 256) {
        const int row = j / 120;
        const int c   = j - row * 120;
        const float* Wp;
        int stride;
        if (c < 50)       { Wp = W_country + c;        stride = NC_N;  }
        else if (c == 50) { Wp = W_type;               stride = 1;     }
        else if (c < 56)  { Wp = W_taste + (c - 51);   stride = NT_N;  }
        else if (c < 88)  { Wp = W_grape + (c - 56);   stride = E_DIM; }
        else              { Wp = W_aroma + (c - 88);   stride = E_DIM; }
        float acc = 0.f;
        const float* yv = ys[row];
        #pragma unroll 4
        for (int k = 0; k < H_DIM; ++k)
            acc += yv[k] * Wp[(size_t)k * stride];
        const int b = b0 + row;
        if (c < 50) {
            out[O_COUNTRY + (size_t)b * NC_N + c] = acc + b_country[c];
        } else if (c == 50) {
            out[O_TYPE + b] = sigmoidf_(acc + b_type[0]);
        } else if (c < 56) {
            out[O_TASTE + (size_t)b * NT_N + (c - 51)] = sigmoidf_(acc + b_taste[c - 51]);
        } else if (c < 88) {
            yg[row][c - 56] = acc + b_grape[c - 56];
        } else {
            ya[row][c - 88] = acc + b_aroma[c - 88];
        }
    }
    __syncthreads();

    // ---------- Phase 4: ragged gathers ----------
    if (t < ROWS * KG_N) {                       // 32 grape jobs
        const int row  = t >> 3;
        const int gi   = (b0 + row) * KG_N + (t & 7);
        const int idx  = grapes[gi];
        float pred = 0.f;
        if (idx != 0) {
            const float* ep = grapes_emb + (size_t)idx * E_DIM;
            const float* yv = yg[row];
            float acc = 0.f;
            #pragma unroll
            for (int e = 0; e < E_DIM; e += 4) {
                float4 v = *(const float4*)(ep + e);
                acc += yv[e+0]*v.x + yv[e+1]*v.y + yv[e+2]*v.z + yv[e+3]*v.w;
            }
            pred = sigmoidf_(acc);
        }
        out[O_GPRED + gi] = pred;
        out[O_GTRUE + gi] = grapes_scales[gi];   // scales*(scales!=0) == scales, exact
    } else if (t < ROWS * (KG_N + KA_N)) {       // 80 aroma jobs
        const int j    = t - ROWS * KG_N;
        const int row  = j / KA_N;
        const int ai   = (b0 + row) * KA_N + (j - row * KA_N);
        const float sc = aromas_scales[ai];
        float pred = 0.f;
        if (sc != 0.f) {                         // mask = (scales != 0)
            const int idx = aromas[ai];
            const float* ep = aroma_emb + (size_t)idx * E_DIM;
            const float* yv = ya[row];
            float acc = 0.f;
            #pragma unroll
            for (int e = 0; e < E_DIM; e += 4) {
                float4 v = *(const float4*)(ep + e);
                acc += yv[e+0]*v.x + yv[e+1]*v.y + yv[e+2]*v.z + yv[e+3]*v.w;
            }
            pred = sigmoidf_(acc);
        }
        out[O_APRED + ai] = pred;
        out[O_ATRUE + ai] = sc;                  // scales * mask == scales, exact
    }
}

extern "C" void kernel_launch(void* const* d_in, const int* in_sizes, int n_in,
                              void* d_out, int out_size, void* d_ws, size_t ws_size,
                              hipStream_t stream) {
    (void)in_sizes; (void)n_in; (void)d_ws; (void)ws_size; (void)out_size;
    const float* x_enc         = (const float*)d_in[0];
    const int*   grapes        = (const int*)  d_in[1];
    const float* grapes_scales = (const float*)d_in[2];
    const int*   aromas        = (const int*)  d_in[3];
    const float* aromas_scales = (const float*)d_in[4];
    const float* W_common      = (const float*)d_in[5];
    const float* b_common      = (const float*)d_in[6];
    const float* W_country     = (const float*)d_in[7];
    const float* b_country     = (const float*)d_in[8];
    const float* W_type        = (const float*)d_in[9];
    const float* b_type        = (const float*)d_in[10];
    const float* W_taste       = (const float*)d_in[11];
    const float* b_taste       = (const float*)d_in[12];
    const float* W_aroma       = (const float*)d_in[13];
    const float* b_aroma       = (const float*)d_in[14];
    const float* W_grape       = (const float*)d_in[15];
    const float* b_grape       = (const float*)d_in[16];
    const float* grapes_emb    = (const float*)d_in[17];
    const float* aroma_emb     = (const float*)d_in[18];
    float* out = (float*)d_out;

    hipLaunchKernelGGL(wine_fused_kernel, dim3(NBLK), dim3(256), 0, stream,
                       x_enc, grapes, grapes_scales, aromas, aromas_scales,
                       W_common, b_common, W_country, b_country, W_type, b_type,
                       W_taste, b_taste, W_aroma, b_aroma, W_grape, b_grape,
                       grapes_emb, aroma_emb, out);
}